// Round 1
// baseline (1961.477 us; speedup 1.0000x reference)
//
#include <hip/hip_runtime.h>
#include <math.h>

#define IN_D 64
#define HID_D 128
#define OUT_D 64

// Decode edge_index (robust to int32 or int64 storage) and accumulate in-degree.
__global__ void k_decode(const unsigned int* __restrict__ raw, int E,
                         int* __restrict__ src, int* __restrict__ dst,
                         float* __restrict__ deg) {
    __shared__ int is64;
    if (threadIdx.x == 0) {
        int f = 1;
        for (int i = 1; i < 64; i += 2) f &= (raw[i] == 0u);
        is64 = f;
    }
    __syncthreads();
    int e = blockIdx.x * blockDim.x + threadIdx.x;
    if (e >= E) return;
    int s, d;
    if (is64) {
        s = (int)raw[2 * (size_t)e];
        d = (int)raw[2 * ((size_t)E + e)];
    } else {
        s = (int)raw[e];
        d = (int)raw[E + e];
    }
    src[e] = s;
    dst[e] = d;
    unsafeAtomicAdd(&deg[d], 1.0f);
}

__global__ void k_dinv(float* __restrict__ deg, int N) {
    int i = blockIdx.x * blockDim.x + threadIdx.x;
    if (i < N) deg[i] = rsqrtf(deg[i] + 1.0f);  // +1 = self loop
}

// agg[i] = dinv[i]^2 * feat[i]   (self-loop term), feat is [N,64]
__global__ void k_init_agg(const float* __restrict__ feat, const float* __restrict__ dinv,
                           float* __restrict__ agg, int N) {
    int idx = blockIdx.x * blockDim.x + threadIdx.x;
    if (idx >= N * 16) return;
    int i = idx >> 4, c = idx & 15;
    float w = dinv[i]; w *= w;
    float4 v = ((const float4*)feat)[(size_t)i * 16 + c];
    v.x *= w; v.y *= w; v.z *= w; v.w *= w;
    ((float4*)agg)[(size_t)i * 16 + c] = v;
}

// agg[dst] += dinv[src]*dinv[dst] * feat[src], feat/agg [N,64]; 16 threads/edge
__global__ void k_scatter64(const float* __restrict__ feat, const float* __restrict__ dinv,
                            const int* __restrict__ src, const int* __restrict__ dst,
                            float* __restrict__ agg, int E) {
    int idx = blockIdx.x * blockDim.x + threadIdx.x;
    int e = idx >> 4, c = idx & 15;
    if (e >= E) return;
    int s = src[e], d = dst[e];
    float norm = dinv[s] * dinv[d];
    float4 v = ((const float4*)feat)[(size_t)s * 16 + c];
    float* o = agg + (size_t)d * 64 + c * 4;
    unsafeAtomicAdd(o + 0, v.x * norm);
    unsafeAtomicAdd(o + 1, v.y * norm);
    unsafeAtomicAdd(o + 2, v.z * norm);
    unsafeAtomicAdd(o + 3, v.w * norm);
}

// out[N,128] = relu(A[N,64] @ W[64,128] + b), 16 nodes/block
__global__ __launch_bounds__(256) void k_gemm1(const float* __restrict__ A,
                                               const float* __restrict__ W,
                                               const float* __restrict__ b,
                                               float* __restrict__ out, int N) {
    __shared__ float wl[64 * 128];
    __shared__ float al[16 * 64];
    for (int i = threadIdx.x; i < 64 * 128; i += 256) wl[i] = W[i];
    int n0 = blockIdx.x * 16;
    for (int i = threadIdx.x; i < 16 * 64; i += 256) {
        size_t gi = (size_t)n0 * 64 + i;
        al[i] = (gi < (size_t)N * 64) ? A[gi] : 0.0f;
    }
    __syncthreads();
    int j = threadIdx.x & 127;
    int ln = threadIdx.x >> 7;  // 0..1
    float bj = b[j];
    for (int s2 = 0; s2 < 8; ++s2) {
        int lnode = s2 * 2 + ln;
        int node = n0 + lnode;
        float acc = bj;
        const float* ar = al + lnode * 64;
#pragma unroll
        for (int k = 0; k < 64; ++k) acc = fmaf(ar[k], wl[k * 128 + j], acc);
        if (node < N) out[(size_t)node * 128 + j] = fmaxf(acc, 0.0f);
    }
}

// out[N,64] = A[N,128] @ W[128,64]   (no bias/relu), 16 nodes/block
__global__ __launch_bounds__(256) void k_gemm2(const float* __restrict__ A,
                                               const float* __restrict__ W,
                                               float* __restrict__ out, int N) {
    __shared__ float wl[128 * 64];
    __shared__ float al[16 * 128];
    for (int i = threadIdx.x; i < 128 * 64; i += 256) wl[i] = W[i];
    int n0 = blockIdx.x * 16;
    for (int i = threadIdx.x; i < 16 * 128; i += 256) {
        size_t gi = (size_t)n0 * 128 + i;
        al[i] = (gi < (size_t)N * 128) ? A[gi] : 0.0f;
    }
    __syncthreads();
    int j = threadIdx.x & 63;
    int ln = threadIdx.x >> 6;  // 0..3
    for (int s4 = 0; s4 < 4; ++s4) {
        int lnode = s4 * 4 + ln;
        int node = n0 + lnode;
        float acc = 0.0f;
        const float* ar = al + lnode * 128;
#pragma unroll
        for (int k = 0; k < 128; ++k) acc = fmaf(ar[k], wl[k * 64 + j], acc);
        if (node < N) out[(size_t)node * 64 + j] = acc;
    }
}

// per-node: v = relu(agg+b2); s0 = dot(v, Wc[0:64]); s1 = dot(v, Wc[64:128])
__global__ void k_scores(const float* __restrict__ agg, const float* __restrict__ b2,
                         const float* __restrict__ Wc,
                         float* __restrict__ s0, float* __restrict__ s1, int N) {
    int i = blockIdx.x * 4 + (threadIdx.x >> 6);
    int lane = threadIdx.x & 63;
    if (i >= N) return;
    float v = fmaxf(agg[(size_t)i * 64 + lane] + b2[lane], 0.0f);
    float p0 = v * Wc[lane];
    float p1 = v * Wc[64 + lane];
#pragma unroll
    for (int off = 32; off > 0; off >>= 1) {
        p0 += __shfl_down(p0, off);
        p1 += __shfl_down(p1, off);
    }
    if (lane == 0) { s0[i] = p0; s1[i] = p1; }
}

__global__ void k_edge(const int* __restrict__ src, const int* __restrict__ dst,
                       const float* __restrict__ s0, const float* __restrict__ s1,
                       const float* __restrict__ bc, float* __restrict__ out, int E) {
    int e = blockIdx.x * blockDim.x + threadIdx.x;
    if (e >= E) return;
    float z = s0[src[e]] + s1[dst[e]] + bc[0];
    out[e] = 1.0f / (1.0f + expf(-z));
}

extern "C" void kernel_launch(void* const* d_in, const int* in_sizes, int n_in,
                              void* d_out, int out_size, void* d_ws, size_t ws_size,
                              hipStream_t stream) {
    const float* x  = (const float*)d_in[0];
    const unsigned int* eidx = (const unsigned int*)d_in[1];
    const float* W1 = (const float*)d_in[2];
    const float* b1 = (const float*)d_in[3];
    const float* W2 = (const float*)d_in[4];
    const float* b2 = (const float*)d_in[5];
    const float* Wc = (const float*)d_in[6];
    const float* bc = (const float*)d_in[7];
    float* out = (float*)d_out;

    int N = in_sizes[0] / IN_D;
    int E = in_sizes[1] / 2;

    char* p = (char*)d_ws;
    int*   src  = (int*)p;    p += (size_t)E * 4;
    int*   dst  = (int*)p;    p += (size_t)E * 4;
    float* dinv = (float*)p;  p += (size_t)N * 4;   // deg then dinv (in place)
    float* agg  = (float*)p;  p += (size_t)N * 64 * 4;  // layer1 agg, reused for layer2 agg
    float* h1   = (float*)p;  p += (size_t)N * 128 * 4;
    float* t    = (float*)p;  p += (size_t)N * 64 * 4;
    float* s0   = (float*)p;  p += (size_t)N * 4;
    float* s1   = (float*)p;  p += (size_t)N * 4;

    hipMemsetAsync(dinv, 0, (size_t)N * 4, stream);

    k_decode<<<(E + 255) / 256, 256, 0, stream>>>(eidx, E, src, dst, dinv);
    k_dinv<<<(N + 255) / 256, 256, 0, stream>>>(dinv, N);

    // Layer 1: aggregate x (64-d), then GEMM 64->128 (+b1, relu)
    k_init_agg<<<(N * 16 + 255) / 256, 256, 0, stream>>>(x, dinv, agg, N);
    k_scatter64<<<((size_t)E * 16 + 255) / 256, 256, 0, stream>>>(x, dinv, src, dst, agg, E);
    k_gemm1<<<(N + 15) / 16, 256, 0, stream>>>(agg, W1, b1, h1, N);

    // Layer 2: GEMM 128->64 first, then aggregate (64-d)
    k_gemm2<<<(N + 15) / 16, 256, 0, stream>>>(h1, W2, t, N);
    k_init_agg<<<(N * 16 + 255) / 256, 256, 0, stream>>>(t, dinv, agg, N);
    k_scatter64<<<((size_t)E * 16 + 255) / 256, 256, 0, stream>>>(t, dinv, src, dst, agg, E);

    // Per-node scores (fuses +b2, relu, both Wc dots), then per-edge sigmoid
    k_scores<<<(N + 3) / 4, 256, 0, stream>>>(agg, b2, Wc, s0, s1, N);
    k_edge<<<(E + 255) / 256, 256, 0, stream>>>(src, dst, s0, s1, bc, out, E);
}

// Round 2
// 571.974 us; speedup vs baseline: 3.4293x; 3.4293x over previous
//
#include <hip/hip_runtime.h>
#include <math.h>

#define IN_D 64
#define HID_D 128
#define OUT_D 64

// ---------------------------------------------------------------------------
// Decode edge_index (robust to int32 or int64 storage) + int in-degree histogram
__global__ void k_decode(const unsigned int* __restrict__ raw, int E,
                         int* __restrict__ src, int* __restrict__ dst,
                         int* __restrict__ deg) {
    __shared__ int is64;
    if (threadIdx.x == 0) {
        int f = 1;
        for (int i = 1; i < 64; i += 2) f &= (raw[i] == 0u);
        is64 = f;
    }
    __syncthreads();
    int e = blockIdx.x * blockDim.x + threadIdx.x;
    if (e >= E) return;
    int s, d;
    if (is64) {
        s = (int)raw[2 * (size_t)e];
        d = (int)raw[2 * ((size_t)E + e)];
    } else {
        s = (int)raw[e];
        d = (int)raw[E + e];
    }
    src[e] = s;
    dst[e] = d;
    atomicAdd(&deg[d], 1);
}

// ---------------------------------------------------------------------------
// Exclusive scan of deg -> row_ptr (3 kernels: block scan, scan of block sums, add)
__global__ void k_scanA(const int* __restrict__ deg, int* __restrict__ part,
                        int* __restrict__ blksum, int N) {
    int i = blockIdx.x * 256 + threadIdx.x;
    int v = (i < N) ? deg[i] : 0;
    int lane = threadIdx.x & 63, w = threadIdx.x >> 6;
    for (int off = 1; off < 64; off <<= 1) {
        int n = __shfl_up(v, off);
        if (lane >= off) v += n;
    }
    __shared__ int wsum[4];
    if (lane == 63) wsum[w] = v;
    __syncthreads();
    for (int k = 0; k < w; ++k) v += wsum[k];
    if (i < N) part[i] = v;                       // inclusive within block
    if (threadIdx.x == 255) blksum[blockIdx.x] = v;
}

__global__ void k_scanB(int* __restrict__ blksum, int nb) {
    int t = threadIdx.x;  // 512 threads, nb <= 512
    int v = (t < nb) ? blksum[t] : 0;
    int orig = v;
    int lane = t & 63, w = t >> 6;
    for (int off = 1; off < 64; off <<= 1) {
        int n = __shfl_up(v, off);
        if (lane >= off) v += n;
    }
    __shared__ int wsum[8];
    if (lane == 63) wsum[w] = v;
    __syncthreads();
    for (int k = 0; k < w; ++k) v += wsum[k];
    if (t < nb) blksum[t] = v - orig;             // exclusive block offsets
}

__global__ void k_scanC(const int* __restrict__ deg, const int* __restrict__ part,
                        const int* __restrict__ blksum, int* __restrict__ row_ptr,
                        int* __restrict__ cursor, float* __restrict__ dinv,
                        int N, int E) {
    int i = blockIdx.x * 256 + threadIdx.x;
    if (i == 0) row_ptr[N] = E;
    if (i >= N) return;
    int start = part[i] - deg[i] + blksum[blockIdx.x];  // exclusive scan
    row_ptr[i] = start;
    cursor[i] = start;
    dinv[i] = rsqrtf((float)deg[i] + 1.0f);             // +1 = self loop
}

__global__ void k_place(const int* __restrict__ src, const int* __restrict__ dst,
                        int* __restrict__ cursor, int* __restrict__ csr_src, int E) {
    int e = blockIdx.x * blockDim.x + threadIdx.x;
    if (e >= E) return;
    int pos = atomicAdd(&cursor[dst[e]], 1);
    csr_src[pos] = src[e];
}

// ---------------------------------------------------------------------------
// agg[i,:] = dinv[i] * ( dinv[i]*feat[i,:] + sum_{s in N_in(i)} dinv[s]*feat[s,:] )
// one 64-lane wave per node, lane = column
__global__ void k_gather64(const float* __restrict__ feat, const float* __restrict__ dinv,
                           const int* __restrict__ row_ptr, const int* __restrict__ csr_src,
                           float* __restrict__ agg, int N) {
    int node = blockIdx.x * 4 + (threadIdx.x >> 6);
    int lane = threadIdx.x & 63;
    if (node >= N) return;
    int beg = row_ptr[node], end = row_ptr[node + 1];
    float di = dinv[node];
    float acc = di * feat[(size_t)node * 64 + lane];
    for (int k = beg; k < end; ++k) {
        int s = csr_src[k];
        acc += dinv[s] * feat[(size_t)s * 64 + lane];
    }
    agg[(size_t)node * 64 + lane] = acc * di;
}

// Layer-2 aggregation fused with +b2, relu, and the two Wc dot products.
__global__ void k_gather_scores(const float* __restrict__ feat, const float* __restrict__ dinv,
                                const int* __restrict__ row_ptr, const int* __restrict__ csr_src,
                                const float* __restrict__ b2, const float* __restrict__ Wc,
                                float* __restrict__ s0, float* __restrict__ s1, int N) {
    int node = blockIdx.x * 4 + (threadIdx.x >> 6);
    int lane = threadIdx.x & 63;
    if (node >= N) return;
    int beg = row_ptr[node], end = row_ptr[node + 1];
    float di = dinv[node];
    float acc = di * feat[(size_t)node * 64 + lane];
    for (int k = beg; k < end; ++k) {
        int s = csr_src[k];
        acc += dinv[s] * feat[(size_t)s * 64 + lane];
    }
    float v = fmaxf(acc * di + b2[lane], 0.0f);
    float p0 = v * Wc[lane];
    float p1 = v * Wc[64 + lane];
#pragma unroll
    for (int off = 32; off > 0; off >>= 1) {
        p0 += __shfl_down(p0, off);
        p1 += __shfl_down(p1, off);
    }
    if (lane == 0) { s0[node] = p0; s1[node] = p1; }
}

// ---------------------------------------------------------------------------
// out[N,128] = relu(A[N,64] @ W[64,128] + b), 16 nodes/block
__global__ __launch_bounds__(256) void k_gemm1(const float* __restrict__ A,
                                               const float* __restrict__ W,
                                               const float* __restrict__ b,
                                               float* __restrict__ out, int N) {
    __shared__ float wl[64 * 128];
    __shared__ float al[16 * 64];
    for (int i = threadIdx.x; i < 64 * 128; i += 256) wl[i] = W[i];
    int n0 = blockIdx.x * 16;
    for (int i = threadIdx.x; i < 16 * 64; i += 256) {
        size_t gi = (size_t)n0 * 64 + i;
        al[i] = (gi < (size_t)N * 64) ? A[gi] : 0.0f;
    }
    __syncthreads();
    int j = threadIdx.x & 127;
    int ln = threadIdx.x >> 7;
    float bj = b[j];
    for (int s2 = 0; s2 < 8; ++s2) {
        int lnode = s2 * 2 + ln;
        int node = n0 + lnode;
        float acc = bj;
        const float* ar = al + lnode * 64;
#pragma unroll
        for (int k = 0; k < 64; ++k) acc = fmaf(ar[k], wl[k * 128 + j], acc);
        if (node < N) out[(size_t)node * 128 + j] = fmaxf(acc, 0.0f);
    }
}

// out[N,64] = A[N,128] @ W[128,64]   (no bias/relu), 16 nodes/block
__global__ __launch_bounds__(256) void k_gemm2(const float* __restrict__ A,
                                               const float* __restrict__ W,
                                               float* __restrict__ out, int N) {
    __shared__ float wl[128 * 64];
    __shared__ float al[16 * 128];
    for (int i = threadIdx.x; i < 128 * 64; i += 256) wl[i] = W[i];
    int n0 = blockIdx.x * 16;
    for (int i = threadIdx.x; i < 16 * 128; i += 256) {
        size_t gi = (size_t)n0 * 128 + i;
        al[i] = (gi < (size_t)N * 128) ? A[gi] : 0.0f;
    }
    __syncthreads();
    int j = threadIdx.x & 63;
    int ln = threadIdx.x >> 6;
    for (int s4 = 0; s4 < 4; ++s4) {
        int lnode = s4 * 4 + ln;
        int node = n0 + lnode;
        float acc = 0.0f;
        const float* ar = al + lnode * 128;
#pragma unroll
        for (int k = 0; k < 128; ++k) acc = fmaf(ar[k], wl[k * 64 + j], acc);
        if (node < N) out[(size_t)node * 64 + j] = acc;
    }
}

__global__ void k_edge(const int* __restrict__ src, const int* __restrict__ dst,
                       const float* __restrict__ s0, const float* __restrict__ s1,
                       const float* __restrict__ bc, float* __restrict__ out, int E) {
    int e = blockIdx.x * blockDim.x + threadIdx.x;
    if (e >= E) return;
    float z = s0[src[e]] + s1[dst[e]] + bc[0];
    out[e] = 1.0f / (1.0f + expf(-z));
}

// ---------------------------------------------------------------------------
extern "C" void kernel_launch(void* const* d_in, const int* in_sizes, int n_in,
                              void* d_out, int out_size, void* d_ws, size_t ws_size,
                              hipStream_t stream) {
    const float* x  = (const float*)d_in[0];
    const unsigned int* eidx = (const unsigned int*)d_in[1];
    const float* W1 = (const float*)d_in[2];
    const float* b1 = (const float*)d_in[3];
    const float* W2 = (const float*)d_in[4];
    const float* b2 = (const float*)d_in[5];
    const float* Wc = (const float*)d_in[6];
    const float* bc = (const float*)d_in[7];
    float* out = (float*)d_out;

    int N = in_sizes[0] / IN_D;
    int E = in_sizes[1] / 2;
    int nblkN = (N + 255) / 256;   // 391 for N=100k (<= 512 for scanB)

    char* p = (char*)d_ws;
    int*   src     = (int*)p;   p += (size_t)E * 4;
    int*   dst     = (int*)p;   p += (size_t)E * 4;
    int*   deg     = (int*)p;   p += (size_t)N * 4;
    int*   part    = (int*)p;   p += (size_t)N * 4;
    int*   blksum  = (int*)p;   p += 512 * 4;
    int*   row_ptr = (int*)p;   p += (size_t)(N + 1) * 4;
    int*   cursor  = (int*)p;   p += (size_t)N * 4;
    int*   csr_src = (int*)p;   p += (size_t)E * 4;
    float* dinv    = (float*)p; p += (size_t)N * 4;
    float* aggT    = (float*)p; p += (size_t)N * 64 * 4;   // layer-1 agg, then layer-2 t
    float* h1      = (float*)p; p += (size_t)N * 128 * 4;
    float* s0      = (float*)p; p += (size_t)N * 4;
    float* s1      = (float*)p; p += (size_t)N * 4;

    hipMemsetAsync(deg, 0, (size_t)N * 4, stream);

    // CSR build (counting sort by dst)
    k_decode<<<(E + 255) / 256, 256, 0, stream>>>(eidx, E, src, dst, deg);
    k_scanA<<<nblkN, 256, 0, stream>>>(deg, part, blksum, N);
    k_scanB<<<1, 512, 0, stream>>>(blksum, nblkN);
    k_scanC<<<nblkN, 256, 0, stream>>>(deg, part, blksum, row_ptr, cursor, dinv, N, E);
    k_place<<<(E + 255) / 256, 256, 0, stream>>>(src, dst, cursor, csr_src, E);

    // Layer 1: aggregate x (64-d) by gather, then GEMM 64->128 (+b1, relu)
    k_gather64<<<(N + 3) / 4, 256, 0, stream>>>(x, dinv, row_ptr, csr_src, aggT, N);
    k_gemm1<<<(N + 15) / 16, 256, 0, stream>>>(aggT, W1, b1, h1, N);

    // Layer 2: GEMM 128->64 first, then aggregate + fused scores
    k_gemm2<<<(N + 15) / 16, 256, 0, stream>>>(h1, W2, aggT, N);
    k_gather_scores<<<(N + 3) / 4, 256, 0, stream>>>(aggT, dinv, row_ptr, csr_src,
                                                     b2, Wc, s0, s1, N);

    // Per-edge sigmoid from per-node partial scores
    k_edge<<<(E + 255) / 256, 256, 0, stream>>>(src, dst, s0, s1, bc, out, E);
}

// Round 3
// 415.841 us; speedup vs baseline: 4.7169x; 1.3755x over previous
//
#include <hip/hip_runtime.h>
#include <hip/hip_fp16.h>
#include <math.h>

#define IN_D 64
#define HID_D 128
#define OUT_D 64

// ---------------------------------------------------------------------------
// Decode edge_index (robust to int32 or int64 storage) + int in-degree histogram
__global__ void k_decode(const unsigned int* __restrict__ raw, int E,
                         int* __restrict__ src, int* __restrict__ dst,
                         int* __restrict__ deg) {
    __shared__ int is64;
    if (threadIdx.x == 0) {
        int f = 1;
        for (int i = 1; i < 64; i += 2) f &= (raw[i] == 0u);
        is64 = f;
    }
    __syncthreads();
    int e = blockIdx.x * blockDim.x + threadIdx.x;
    if (e >= E) return;
    int s, d;
    if (is64) {
        s = (int)raw[2 * (size_t)e];
        d = (int)raw[2 * ((size_t)E + e)];
    } else {
        s = (int)raw[e];
        d = (int)raw[E + e];
    }
    src[e] = s;
    dst[e] = d;
    atomicAdd(&deg[d], 1);
}

// ---------------------------------------------------------------------------
// Exclusive scan of deg -> row_ptr
__global__ void k_scanA(const int* __restrict__ deg, int* __restrict__ part,
                        int* __restrict__ blksum, int N) {
    int i = blockIdx.x * 256 + threadIdx.x;
    int v = (i < N) ? deg[i] : 0;
    int lane = threadIdx.x & 63, w = threadIdx.x >> 6;
    for (int off = 1; off < 64; off <<= 1) {
        int n = __shfl_up(v, off);
        if (lane >= off) v += n;
    }
    __shared__ int wsum[4];
    if (lane == 63) wsum[w] = v;
    __syncthreads();
    for (int k = 0; k < w; ++k) v += wsum[k];
    if (i < N) part[i] = v;
    if (threadIdx.x == 255) blksum[blockIdx.x] = v;
}

__global__ void k_scanB(int* __restrict__ blksum, int nb) {
    int t = threadIdx.x;  // 512 threads, nb <= 512
    int v = (t < nb) ? blksum[t] : 0;
    int orig = v;
    int lane = t & 63, w = t >> 6;
    for (int off = 1; off < 64; off <<= 1) {
        int n = __shfl_up(v, off);
        if (lane >= off) v += n;
    }
    __shared__ int wsum[8];
    if (lane == 63) wsum[w] = v;
    __syncthreads();
    for (int k = 0; k < w; ++k) v += wsum[k];
    if (t < nb) blksum[t] = v - orig;
}

__global__ void k_scanC(const int* __restrict__ deg, const int* __restrict__ part,
                        const int* __restrict__ blksum, int* __restrict__ row_ptr,
                        int* __restrict__ cursor, float* __restrict__ dinv,
                        int N, int E) {
    int i = blockIdx.x * 256 + threadIdx.x;
    if (i == 0) row_ptr[N] = E;
    if (i >= N) return;
    int start = part[i] - deg[i] + blksum[blockIdx.x];
    row_ptr[i] = start;
    cursor[i] = start;
    dinv[i] = rsqrtf((float)deg[i] + 1.0f);  // +1 = self loop
}

__global__ void k_place(const int* __restrict__ src, const int* __restrict__ dst,
                        int* __restrict__ cursor, int* __restrict__ csr_src, int E) {
    int e = blockIdx.x * blockDim.x + threadIdx.x;
    if (e >= E) return;
    int pos = atomicAdd(&cursor[dst[e]], 1);
    csr_src[pos] = src[e];
}

// ---------------------------------------------------------------------------
// xs[i,:] = fp16( dinv[i] * x[i,:] )   (pre-scaled features, halves gather bytes)
__global__ void k_xconv(const float* __restrict__ x, const float* __restrict__ dinv,
                        __half* __restrict__ xs, int N) {
    int idx = blockIdx.x * blockDim.x + threadIdx.x;
    if (idx >= N * 32) return;
    int i = idx >> 5, c = (idx & 31) * 2;
    float di = dinv[i];
    float2 v = *(const float2*)&x[(size_t)i * 64 + c];
    *(__half2*)&xs[(size_t)i * 64 + c] = __floats2half2_rn(v.x * di, v.y * di);
}

// ---------------------------------------------------------------------------
// agg[i,:] = dinv[i] * ( xs[i,:] + sum_{s in N_in(i)} xs[s,:] )     (xs pre-scaled)
// one 64-lane wave per node, lane = column; 4-deep unrolled gather
__global__ void k_gather1(const __half* __restrict__ xs, const float* __restrict__ dinv,
                          const int* __restrict__ row_ptr, const int* __restrict__ csr_src,
                          float* __restrict__ agg, int N) {
    int node = blockIdx.x * 4 + (threadIdx.x >> 6);
    int lane = threadIdx.x & 63;
    if (node >= N) return;
    int beg = row_ptr[node], end = row_ptr[node + 1];
    float acc = __half2float(xs[(size_t)node * 64 + lane]);
    int k = beg;
    for (; k + 4 <= end; k += 4) {
        int s0 = csr_src[k], s1 = csr_src[k + 1], s2 = csr_src[k + 2], s3 = csr_src[k + 3];
        float a0 = __half2float(xs[(size_t)s0 * 64 + lane]);
        float a1 = __half2float(xs[(size_t)s1 * 64 + lane]);
        float a2 = __half2float(xs[(size_t)s2 * 64 + lane]);
        float a3 = __half2float(xs[(size_t)s3 * 64 + lane]);
        acc += (a0 + a1) + (a2 + a3);
    }
    for (; k < end; ++k)
        acc += __half2float(xs[(size_t)csr_src[k] * 64 + lane]);
    agg[(size_t)node * 64 + lane] = acc * dinv[node];
}

// Layer-2 aggregation fused with +b2, relu, and both Wc dot products.
__global__ void k_gather2_scores(const __half* __restrict__ ts, const float* __restrict__ dinv,
                                 const int* __restrict__ row_ptr, const int* __restrict__ csr_src,
                                 const float* __restrict__ b2, const float* __restrict__ Wc,
                                 float* __restrict__ s0o, float* __restrict__ s1o, int N) {
    int node = blockIdx.x * 4 + (threadIdx.x >> 6);
    int lane = threadIdx.x & 63;
    if (node >= N) return;
    int beg = row_ptr[node], end = row_ptr[node + 1];
    float acc = __half2float(ts[(size_t)node * 64 + lane]);
    int k = beg;
    for (; k + 4 <= end; k += 4) {
        int s0 = csr_src[k], s1 = csr_src[k + 1], s2 = csr_src[k + 2], s3 = csr_src[k + 3];
        float a0 = __half2float(ts[(size_t)s0 * 64 + lane]);
        float a1 = __half2float(ts[(size_t)s1 * 64 + lane]);
        float a2 = __half2float(ts[(size_t)s2 * 64 + lane]);
        float a3 = __half2float(ts[(size_t)s3 * 64 + lane]);
        acc += (a0 + a1) + (a2 + a3);
    }
    for (; k < end; ++k)
        acc += __half2float(ts[(size_t)csr_src[k] * 64 + lane]);
    float v = fmaxf(acc * dinv[node] + b2[lane], 0.0f);
    float p0 = v * Wc[lane];
    float p1 = v * Wc[64 + lane];
#pragma unroll
    for (int off = 32; off > 0; off >>= 1) {
        p0 += __shfl_down(p0, off);
        p1 += __shfl_down(p1, off);
    }
    if (lane == 0) { s0o[node] = p0; s1o[node] = p1; }
}

// ---------------------------------------------------------------------------
// Fused MLP: ts[node,:] = fp16( dinv[node] * ( relu(agg@W1 + b1) @ W2 ) )
// 16 nodes/block; W1+W2+agg+h tiles all in LDS (76 KB -> 2 blocks/CU)
__global__ __launch_bounds__(256) void k_fused_mlp(const float* __restrict__ agg,
                                                   const float* __restrict__ W1,
                                                   const float* __restrict__ b1,
                                                   const float* __restrict__ W2,
                                                   const float* __restrict__ dinv,
                                                   __half* __restrict__ ts, int N) {
    __shared__ float w1l[64 * 128];    // 32 KB
    __shared__ float w2l[128 * 64];    // 32 KB
    __shared__ float al[16 * 64];      // 4 KB
    __shared__ float hl[16 * 129];     // 8.25 KB, +1 pad kills 4-way bank conflict
    for (int i = threadIdx.x; i < 64 * 128; i += 256) w1l[i] = W1[i];
    for (int i = threadIdx.x; i < 128 * 64; i += 256) w2l[i] = W2[i];
    int n0 = blockIdx.x * 16;
    for (int i = threadIdx.x; i < 16 * 64; i += 256) {
        size_t gi = (size_t)n0 * 64 + i;
        al[i] = (gi < (size_t)N * 64) ? agg[gi] : 0.0f;
    }
    __syncthreads();

    // Stage 1: h = relu(agg @ W1 + b1), thread = (col-group of 4, node pair {r, r+8})
    {
        int c4 = (threadIdx.x & 31) * 4;
        int r = threadIdx.x >> 5;  // 0..7
        float4 bb = *(const float4*)&b1[c4];
        float4 acc0 = bb, acc1 = bb;
#pragma unroll
        for (int k = 0; k < 64; ++k) {
            float a0 = al[r * 64 + k];
            float a1 = al[(r + 8) * 64 + k];
            float4 w = *(const float4*)&w1l[k * 128 + c4];
            acc0.x = fmaf(a0, w.x, acc0.x); acc0.y = fmaf(a0, w.y, acc0.y);
            acc0.z = fmaf(a0, w.z, acc0.z); acc0.w = fmaf(a0, w.w, acc0.w);
            acc1.x = fmaf(a1, w.x, acc1.x); acc1.y = fmaf(a1, w.y, acc1.y);
            acc1.z = fmaf(a1, w.z, acc1.z); acc1.w = fmaf(a1, w.w, acc1.w);
        }
        float* h0 = &hl[r * 129 + c4];
        float* h1 = &hl[(r + 8) * 129 + c4];
        h0[0] = fmaxf(acc0.x, 0.f); h0[1] = fmaxf(acc0.y, 0.f);
        h0[2] = fmaxf(acc0.z, 0.f); h0[3] = fmaxf(acc0.w, 0.f);
        h1[0] = fmaxf(acc1.x, 0.f); h1[1] = fmaxf(acc1.y, 0.f);
        h1[2] = fmaxf(acc1.z, 0.f); h1[3] = fmaxf(acc1.w, 0.f);
    }
    __syncthreads();

    // Stage 2: t = h @ W2, thread = (col-group of 4, node r)
    {
        int c4 = (threadIdx.x & 15) * 4;
        int r = threadIdx.x >> 4;  // 0..15
        float4 acc = {0.f, 0.f, 0.f, 0.f};
#pragma unroll
        for (int k = 0; k < 128; ++k) {
            float a = hl[r * 129 + k];
            float4 w = *(const float4*)&w2l[k * 64 + c4];
            acc.x = fmaf(a, w.x, acc.x); acc.y = fmaf(a, w.y, acc.y);
            acc.z = fmaf(a, w.z, acc.z); acc.w = fmaf(a, w.w, acc.w);
        }
        int node = n0 + r;
        if (node < N) {
            float di = dinv[node];
            __half2* tp = (__half2*)&ts[(size_t)node * 64 + c4];
            tp[0] = __floats2half2_rn(acc.x * di, acc.y * di);
            tp[1] = __floats2half2_rn(acc.z * di, acc.w * di);
        }
    }
}

__global__ void k_edge(const int* __restrict__ src, const int* __restrict__ dst,
                       const float* __restrict__ s0, const float* __restrict__ s1,
                       const float* __restrict__ bc, float* __restrict__ out, int E) {
    int e = blockIdx.x * blockDim.x + threadIdx.x;
    if (e >= E) return;
    float z = s0[src[e]] + s1[dst[e]] + bc[0];
    out[e] = 1.0f / (1.0f + expf(-z));
}

// ---------------------------------------------------------------------------
extern "C" void kernel_launch(void* const* d_in, const int* in_sizes, int n_in,
                              void* d_out, int out_size, void* d_ws, size_t ws_size,
                              hipStream_t stream) {
    const float* x  = (const float*)d_in[0];
    const unsigned int* eidx = (const unsigned int*)d_in[1];
    const float* W1 = (const float*)d_in[2];
    const float* b1 = (const float*)d_in[3];
    const float* W2 = (const float*)d_in[4];
    const float* b2 = (const float*)d_in[5];
    const float* Wc = (const float*)d_in[6];
    const float* bc = (const float*)d_in[7];
    float* out = (float*)d_out;

    int N = in_sizes[0] / IN_D;
    int E = in_sizes[1] / 2;
    int nblkN = (N + 255) / 256;  // 391 for N=100k (<= 512 for scanB)

    char* p = (char*)d_ws;
    int*   src     = (int*)p;    p += (size_t)E * 4;
    int*   dst     = (int*)p;    p += (size_t)E * 4;
    int*   deg     = (int*)p;    p += (size_t)N * 4;
    int*   part    = (int*)p;    p += (size_t)N * 4;
    int*   blksum  = (int*)p;    p += 512 * 4;
    int*   row_ptr = (int*)p;    p += (size_t)(N + 1) * 4;
    int*   cursor  = (int*)p;    p += (size_t)N * 4;
    int*   csr_src = (int*)p;    p += (size_t)E * 4;
    float* dinv    = (float*)p;  p += (size_t)N * 4;
    float* agg     = (float*)p;  p += (size_t)N * 64 * 4;
    float* s0      = (float*)p;  p += (size_t)N * 4;
    float* s1      = (float*)p;  p += (size_t)N * 4;
    p += 15; p = (char*)((size_t)p & ~(size_t)15);
    __half* xs     = (__half*)p; p += (size_t)N * 64 * 2;
    __half* ts     = (__half*)p; p += (size_t)N * 64 * 2;

    hipMemsetAsync(deg, 0, (size_t)N * 4, stream);

    // CSR build (counting sort by dst)
    k_decode<<<(E + 255) / 256, 256, 0, stream>>>(eidx, E, src, dst, deg);
    k_scanA<<<nblkN, 256, 0, stream>>>(deg, part, blksum, N);
    k_scanB<<<1, 512, 0, stream>>>(blksum, nblkN);
    k_scanC<<<nblkN, 256, 0, stream>>>(deg, part, blksum, row_ptr, cursor, dinv, N, E);
    k_place<<<(E + 255) / 256, 256, 0, stream>>>(src, dst, cursor, csr_src, E);

    // Pre-scaled fp16 feature table, then layer-1 gather
    k_xconv<<<(N * 32 + 255) / 256, 256, 0, stream>>>(x, dinv, xs, N);
    k_gather1<<<(N + 3) / 4, 256, 0, stream>>>(xs, dinv, row_ptr, csr_src, agg, N);

    // Fused MLP: both GEMMs, relu, dinv pre-scale, fp16 output
    k_fused_mlp<<<(N + 15) / 16, 256, 0, stream>>>(agg, W1, b1, W2, dinv, ts, N);

    // Layer-2 gather fused with b2/relu/Wc scores
    k_gather2_scores<<<(N + 3) / 4, 256, 0, stream>>>(ts, dinv, row_ptr, csr_src,
                                                      b2, Wc, s0, s1, N);

    // Per-edge sigmoid from per-node partial scores
    k_edge<<<(E + 255) / 256, 256, 0, stream>>>(src, dst, s0, s1, bc, out, E);
}

// Round 4
// 335.954 us; speedup vs baseline: 5.8385x; 1.2378x over previous
//
#include <hip/hip_runtime.h>
#include <hip/hip_fp16.h>
#include <math.h>

#define IN_D 64
#define HID_D 128
#define OUT_D 64

typedef _Float16 half8 __attribute__((ext_vector_type(8)));
typedef float f32x4 __attribute__((ext_vector_type(4)));

// ---------------------------------------------------------------------------
// Decode edge_index (robust to int32 or int64 storage) + int in-degree histogram
__global__ void k_decode(const unsigned int* __restrict__ raw, int E,
                         int* __restrict__ src, int* __restrict__ dst,
                         int* __restrict__ deg) {
    __shared__ int is64;
    if (threadIdx.x == 0) {
        int f = 1;
        for (int i = 1; i < 64; i += 2) f &= (raw[i] == 0u);
        is64 = f;
    }
    __syncthreads();
    int e = blockIdx.x * blockDim.x + threadIdx.x;
    if (e >= E) return;
    int s, d;
    if (is64) {
        s = (int)raw[2 * (size_t)e];
        d = (int)raw[2 * ((size_t)E + e)];
    } else {
        s = (int)raw[e];
        d = (int)raw[E + e];
    }
    src[e] = s;
    dst[e] = d;
    atomicAdd(&deg[d], 1);
}

// ---------------------------------------------------------------------------
// Exclusive scan of deg -> row_ptr
__global__ void k_scanA(const int* __restrict__ deg, int* __restrict__ part,
                        int* __restrict__ blksum, int N) {
    int i = blockIdx.x * 256 + threadIdx.x;
    int v = (i < N) ? deg[i] : 0;
    int lane = threadIdx.x & 63, w = threadIdx.x >> 6;
    for (int off = 1; off < 64; off <<= 1) {
        int n = __shfl_up(v, off);
        if (lane >= off) v += n;
    }
    __shared__ int wsum[4];
    if (lane == 63) wsum[w] = v;
    __syncthreads();
    for (int k = 0; k < w; ++k) v += wsum[k];
    if (i < N) part[i] = v;
    if (threadIdx.x == 255) blksum[blockIdx.x] = v;
}

__global__ void k_scanB(int* __restrict__ blksum, int nb) {
    int t = threadIdx.x;  // 512 threads, nb <= 512
    int v = (t < nb) ? blksum[t] : 0;
    int orig = v;
    int lane = t & 63, w = t >> 6;
    for (int off = 1; off < 64; off <<= 1) {
        int n = __shfl_up(v, off);
        if (lane >= off) v += n;
    }
    __shared__ int wsum[8];
    if (lane == 63) wsum[w] = v;
    __syncthreads();
    for (int k = 0; k < w; ++k) v += wsum[k];
    if (t < nb) blksum[t] = v - orig;
}

__global__ void k_scanC(const int* __restrict__ deg, const int* __restrict__ part,
                        const int* __restrict__ blksum, int* __restrict__ row_ptr,
                        int* __restrict__ cursor, float* __restrict__ dinv,
                        int N, int E) {
    int i = blockIdx.x * 256 + threadIdx.x;
    if (i == 0) row_ptr[N] = E;
    if (i >= N) return;
    int start = part[i] - deg[i] + blksum[blockIdx.x];
    row_ptr[i] = start;
    cursor[i] = start;
    dinv[i] = rsqrtf((float)deg[i] + 1.0f);  // +1 = self loop
}

__global__ void k_place(const int* __restrict__ src, const int* __restrict__ dst,
                        int* __restrict__ cursor, int* __restrict__ csr_src, int E) {
    int e = blockIdx.x * blockDim.x + threadIdx.x;
    if (e >= E) return;
    int pos = atomicAdd(&cursor[dst[e]], 1);
    csr_src[pos] = src[e];
}

// ---------------------------------------------------------------------------
// xs[i,:] = fp16( dinv[i] * x[i,:] )
__global__ void k_xconv(const float* __restrict__ x, const float* __restrict__ dinv,
                        __half* __restrict__ xs, int N) {
    int idx = blockIdx.x * blockDim.x + threadIdx.x;
    if (idx >= N * 32) return;
    int i = idx >> 5, c = (idx & 31) * 2;
    float di = dinv[i];
    float2 v = *(const float2*)&x[(size_t)i * 64 + c];
    *(__half2*)&xs[(size_t)i * 64 + c] = __floats2half2_rn(v.x * di, v.y * di);
}

// ---------------------------------------------------------------------------
// Pre-pack W1 (A-operand layout, [8 nt][2 kc]) and W2 (B-operand layout, [4 nt][4 kc])
// into exact MFMA fragment order: frag*512 + lane*8 + j halves.
__global__ void k_wconv(const float* __restrict__ W1, const float* __restrict__ W2,
                        __half* __restrict__ w1f, __half* __restrict__ w2f) {
    int t = blockIdx.x * 256 + threadIdx.x;  // 0..2047
    if (t >= 2048) return;
    int which = t >> 10;
    int fl = t & 1023;            // frag*64 + lane
    int f = fl >> 6, l = fl & 63;
    int q = l >> 4, n16 = l & 15;
    if (which == 0) {             // W1 [64,128], A'-layout: row n = lane&15, k = q*8+j
        int nt = f >> 1, kc = f & 1;
        int n = nt * 16 + n16;
        int k0 = kc * 32 + q * 8;
        for (int j = 0; j < 8; ++j)
            w1f[(size_t)fl * 8 + j] = __float2half(W1[(k0 + j) * 128 + n]);
    } else {                      // W2 [128,64], B-layout: col n = lane&15, k = q*8+j
        int nt = f >> 2, kc = f & 3;
        int n = nt * 16 + n16;
        int k0 = kc * 32 + q * 8;
        for (int j = 0; j < 8; ++j)
            w2f[(size_t)fl * 8 + j] = __float2half(W2[(k0 + j) * 64 + n]);
    }
}

// ---------------------------------------------------------------------------
// Layer-1 gather: agg_h[i,:] = fp16( dinv[i] * (xs[i,:] + sum_{s} xs[s,:]) )
// one wave per node; lane = (slot 0/1)*32 + colpair; 2 neighbors/iter, x4 unroll
__global__ void k_gather1(const __half* __restrict__ xs, const float* __restrict__ dinv,
                          const int* __restrict__ row_ptr, const int* __restrict__ csr_src,
                          __half* __restrict__ agg_h, int N) {
    int node = blockIdx.x * 4 + (threadIdx.x >> 6);
    if (node >= N) return;
    int l = threadIdx.x & 63;
    int slot = l >> 5, c = (l & 31) * 2;
    int beg = row_ptr[node], end = row_ptr[node + 1];
    float ax = 0.f, ay = 0.f;
    int k = beg + slot;
    for (; k + 6 < end; k += 8) {
        int s0 = csr_src[k], s1 = csr_src[k + 2], s2 = csr_src[k + 4], s3 = csr_src[k + 6];
        float2 f0 = __half22float2(*(const __half2*)&xs[(size_t)s0 * 64 + c]);
        float2 f1 = __half22float2(*(const __half2*)&xs[(size_t)s1 * 64 + c]);
        float2 f2 = __half22float2(*(const __half2*)&xs[(size_t)s2 * 64 + c]);
        float2 f3 = __half22float2(*(const __half2*)&xs[(size_t)s3 * 64 + c]);
        ax += (f0.x + f1.x) + (f2.x + f3.x);
        ay += (f0.y + f1.y) + (f2.y + f3.y);
    }
    for (; k < end; k += 2) {
        float2 f = __half22float2(*(const __half2*)&xs[(size_t)csr_src[k] * 64 + c]);
        ax += f.x; ay += f.y;
    }
    ax += __shfl_xor(ax, 32);
    ay += __shfl_xor(ay, 32);
    if (slot == 0) {
        float2 fs = __half22float2(*(const __half2*)&xs[(size_t)node * 64 + c]);
        float di = dinv[node];
        *(__half2*)&agg_h[(size_t)node * 64 + c] =
            __floats2half2_rn((ax + fs.x) * di, (ay + fs.y) * di);
    }
}

// Layer-2 gather fused with +b2, relu, and both Wc dot products.
__global__ void k_gather2_scores(const __half* __restrict__ ts, const float* __restrict__ dinv,
                                 const int* __restrict__ row_ptr, const int* __restrict__ csr_src,
                                 const float* __restrict__ b2, const float* __restrict__ Wc,
                                 float* __restrict__ s0o, float* __restrict__ s1o, int N) {
    int node = blockIdx.x * 4 + (threadIdx.x >> 6);
    if (node >= N) return;
    int l = threadIdx.x & 63;
    int slot = l >> 5, c = (l & 31) * 2;
    int beg = row_ptr[node], end = row_ptr[node + 1];
    float ax = 0.f, ay = 0.f;
    int k = beg + slot;
    for (; k + 6 < end; k += 8) {
        int s0 = csr_src[k], s1 = csr_src[k + 2], s2 = csr_src[k + 4], s3 = csr_src[k + 6];
        float2 f0 = __half22float2(*(const __half2*)&ts[(size_t)s0 * 64 + c]);
        float2 f1 = __half22float2(*(const __half2*)&ts[(size_t)s1 * 64 + c]);
        float2 f2 = __half22float2(*(const __half2*)&ts[(size_t)s2 * 64 + c]);
        float2 f3 = __half22float2(*(const __half2*)&ts[(size_t)s3 * 64 + c]);
        ax += (f0.x + f1.x) + (f2.x + f3.x);
        ay += (f0.y + f1.y) + (f2.y + f3.y);
    }
    for (; k < end; k += 2) {
        float2 f = __half22float2(*(const __half2*)&ts[(size_t)csr_src[k] * 64 + c]);
        ax += f.x; ay += f.y;
    }
    ax += __shfl_xor(ax, 32);
    ay += __shfl_xor(ay, 32);
    float p0 = 0.f, p1 = 0.f;
    if (slot == 0) {
        float2 fs = __half22float2(*(const __half2*)&ts[(size_t)node * 64 + c]);
        float di = dinv[node];
        float2 bb = *(const float2*)&b2[c];
        float vx = fmaxf((ax + fs.x) * di + bb.x, 0.f);
        float vy = fmaxf((ay + fs.y) * di + bb.y, 0.f);
        float2 w0 = *(const float2*)&Wc[c];
        float2 w1 = *(const float2*)&Wc[64 + c];
        p0 = vx * w0.x + vy * w0.y;
        p1 = vx * w1.x + vy * w1.y;
    }
#pragma unroll
    for (int off = 16; off > 0; off >>= 1) {
        p0 += __shfl_down(p0, off);
        p1 += __shfl_down(p1, off);
    }
    if (l == 0) { s0o[node] = p0; s1o[node] = p1; }
}

// ---------------------------------------------------------------------------
// MFMA fused MLP: ts = fp16( dinv * ( relu(agg @ W1 + b1) @ W2 ) )
// 4 waves/block, 16 nodes/wave. Stage 1 computes h^T (W1^T * agg^T) so the
// C->A repack for stage 2 is a pure cross-lane permute (no LDS round-trip).
__global__ __launch_bounds__(256) void k_mlp_mfma(const __half* __restrict__ agg_h,
                                                  const __half* __restrict__ w1f,
                                                  const __half* __restrict__ w2f,
                                                  const float* __restrict__ b1,
                                                  const float* __restrict__ dinv,
                                                  __half* __restrict__ ts, int N) {
    __shared__ __align__(16) __half w1l[8192];   // 16 KB, 16 frags
    __shared__ __align__(16) __half w2l[8192];   // 16 KB, 16 frags
    {
        const float4* sA = (const float4*)w1f;
        const float4* sB = (const float4*)w2f;
        float4* dA = (float4*)w1l;
        float4* dB = (float4*)w2l;
        for (int i = threadIdx.x; i < 1024; i += 256) { dA[i] = sA[i]; dB[i] = sB[i]; }
    }
    __syncthreads();

    int wv = threadIdx.x >> 6, l = threadIdx.x & 63;
    int m0 = blockIdx.x * 64 + wv * 16;
    if (m0 >= N) return;
    int q = l >> 4, ml = l & 15;
    int rowA = m0 + ml; if (rowA >= N) rowA = N - 1;

    // B' fragments: agg rows, k-chunks of 32
    half8 bfr0 = *(const half8*)&agg_h[(size_t)rowA * 64 + q * 8];
    half8 bfr1 = *(const half8*)&agg_h[(size_t)rowA * 64 + 32 + q * 8];

    // Stage 1: D'[n][m] = sum_k W1[k][n] agg[m][k] + b1[n], 8 n-tiles
    int pk[8][2];  // per lane: h[m=ml][n = nt*16 + q*4 + r] packed as 2x half2
#pragma unroll
    for (int nt = 0; nt < 8; ++nt) {
        float4 bb = *(const float4*)&b1[nt * 16 + q * 4];
        f32x4 cacc; cacc[0] = bb.x; cacc[1] = bb.y; cacc[2] = bb.z; cacc[3] = bb.w;
        half8 a0 = *(const half8*)&w1l[(nt * 2 + 0) * 512 + l * 8];
        cacc = __builtin_amdgcn_mfma_f32_16x16x32_f16(a0, bfr0, cacc, 0, 0, 0);
        half8 a1 = *(const half8*)&w1l[(nt * 2 + 1) * 512 + l * 8];
        cacc = __builtin_amdgcn_mfma_f32_16x16x32_f16(a1, bfr1, cacc, 0, 0, 0);
        union { __half2 h; int i; } u0, u1;
        u0.h = __floats2half2_rn(fmaxf(cacc[0], 0.f), fmaxf(cacc[1], 0.f));
        u1.h = __floats2half2_rn(fmaxf(cacc[2], 0.f), fmaxf(cacc[3], 0.f));
        pk[nt][0] = u0.i;
        pk[nt][1] = u1.i;
    }

    // Repack h into stage-2 A-operand fragments via cross-lane permutes.
    int src0 = ml + 16 * ((2 * q) & 3);
    int src1 = ml + 16 * ((2 * q + 1) & 3);
    bool hi = (q >= 2);  // tile select: nts = 2*kc + (q>>1)
    half8 afr[4];
#pragma unroll
    for (int kc = 0; kc < 4; ++kc) {
        int t0 = 2 * kc, t1 = 2 * kc + 1;
        int d0a = __shfl(pk[t0][0], src0), d0b = __shfl(pk[t1][0], src0);
        int d1a = __shfl(pk[t0][1], src0), d1b = __shfl(pk[t1][1], src0);
        int d2a = __shfl(pk[t0][0], src1), d2b = __shfl(pk[t1][0], src1);
        int d3a = __shfl(pk[t0][1], src1), d3b = __shfl(pk[t1][1], src1);
        union { int d[4]; half8 h; } u;
        u.d[0] = hi ? d0b : d0a;
        u.d[1] = hi ? d1b : d1a;
        u.d[2] = hi ? d2b : d2a;
        u.d[3] = hi ? d3b : d3a;
        afr[kc] = u.h;
    }

    // dinv for this wave's 16 nodes, distributed per reg
    float dl = dinv[rowA];
    float dv[4];
#pragma unroll
    for (int r = 0; r < 4; ++r) dv[r] = __shfl(dl, q * 4 + r);

    // Stage 2: D2[m][n2] = h @ W2, 4 n-tiles; scale by dinv, store fp16
#pragma unroll
    for (int nt2 = 0; nt2 < 4; ++nt2) {
        f32x4 cacc; cacc[0] = 0.f; cacc[1] = 0.f; cacc[2] = 0.f; cacc[3] = 0.f;
#pragma unroll
        for (int kc = 0; kc < 4; ++kc) {
            half8 b = *(const half8*)&w2l[(nt2 * 4 + kc) * 512 + l * 8];
            cacc = __builtin_amdgcn_mfma_f32_16x16x32_f16(afr[kc], b, cacc, 0, 0, 0);
        }
#pragma unroll
        for (int r = 0; r < 4; ++r) {
            int node = m0 + q * 4 + r;
            if (node < N)
                ts[(size_t)node * 64 + nt2 * 16 + ml] = __float2half(cacc[r] * dv[r]);
        }
    }
}

__global__ void k_edge(const int* __restrict__ src, const int* __restrict__ dst,
                       const float* __restrict__ s0, const float* __restrict__ s1,
                       const float* __restrict__ bc, float* __restrict__ out, int E) {
    int e = blockIdx.x * blockDim.x + threadIdx.x;
    if (e >= E) return;
    float z = s0[src[e]] + s1[dst[e]] + bc[0];
    out[e] = 1.0f / (1.0f + expf(-z));
}

// ---------------------------------------------------------------------------
extern "C" void kernel_launch(void* const* d_in, const int* in_sizes, int n_in,
                              void* d_out, int out_size, void* d_ws, size_t ws_size,
                              hipStream_t stream) {
    const float* x  = (const float*)d_in[0];
    const unsigned int* eidx = (const unsigned int*)d_in[1];
    const float* W1 = (const float*)d_in[2];
    const float* b1 = (const float*)d_in[3];
    const float* W2 = (const float*)d_in[4];
    const float* b2 = (const float*)d_in[5];
    const float* Wc = (const float*)d_in[6];
    const float* bc = (const float*)d_in[7];
    float* out = (float*)d_out;

    int N = in_sizes[0] / IN_D;
    int E = in_sizes[1] / 2;
    int nblkN = (N + 255) / 256;  // 391 for N=100k (<= 512 for scanB)

    char* p = (char*)d_ws;
    int*   src     = (int*)p;    p += (size_t)E * 4;
    int*   dst     = (int*)p;    p += (size_t)E * 4;
    int*   deg     = (int*)p;    p += (size_t)N * 4;
    int*   part    = (int*)p;    p += (size_t)N * 4;
    int*   blksum  = (int*)p;    p += 512 * 4;
    int*   row_ptr = (int*)p;    p += (size_t)(N + 1) * 4;
    int*   cursor  = (int*)p;    p += (size_t)N * 4;
    int*   csr_src = (int*)p;    p += (size_t)E * 4;
    float* dinv    = (float*)p;  p += (size_t)N * 4;
    float* s0      = (float*)p;  p += (size_t)N * 4;
    float* s1      = (float*)p;  p += (size_t)N * 4;
    p += 15; p = (char*)((size_t)p & ~(size_t)15);
    __half* xs    = (__half*)p;  p += (size_t)N * 64 * 2;
    __half* aggh  = (__half*)p;  p += (size_t)N * 64 * 2;
    __half* ts    = (__half*)p;  p += (size_t)N * 64 * 2;
    __half* w1f   = (__half*)p;  p += 8192 * 2;
    __half* w2f   = (__half*)p;  p += 8192 * 2;

    hipMemsetAsync(deg, 0, (size_t)N * 4, stream);

    // CSR build (counting sort by dst) + weight fragment pre-pack
    k_decode<<<(E + 255) / 256, 256, 0, stream>>>(eidx, E, src, dst, deg);
    k_wconv<<<8, 256, 0, stream>>>(W1, W2, w1f, w2f);
    k_scanA<<<nblkN, 256, 0, stream>>>(deg, part, blksum, N);
    k_scanB<<<1, 512, 0, stream>>>(blksum, nblkN);
    k_scanC<<<nblkN, 256, 0, stream>>>(deg, part, blksum, row_ptr, cursor, dinv, N, E);
    k_place<<<(E + 255) / 256, 256, 0, stream>>>(src, dst, cursor, csr_src, E);

    // Pre-scaled fp16 features, layer-1 gather
    k_xconv<<<(N * 32 + 255) / 256, 256, 0, stream>>>(x, dinv, xs, N);
    k_gather1<<<(N + 3) / 4, 256, 0, stream>>>(xs, dinv, row_ptr, csr_src, aggh, N);

    // MFMA fused MLP
    k_mlp_mfma<<<(N + 63) / 64, 256, 0, stream>>>(aggh, w1f, w2f, b1, dinv, ts, N);

    // Layer-2 gather fused with b2/relu/Wc scores
    k_gather2_scores<<<(N + 3) / 4, 256, 0, stream>>>(ts, dinv, row_ptr, csr_src,
                                                      b2, Wc, s0, s1, N);

    // Per-edge sigmoid from per-node partial scores
    k_edge<<<(E + 255) / 256, 256, 0, stream>>>(src, dst, s0, s1, bc, out, E);
}